// Round 11
// baseline (181.855 us; speedup 1.0000x reference)
//
#include <hip/hip_runtime.h>

#define NCLS 81
#define ROW  85            // 4 loc + 81 logits
#define TPB  256           // no LDS, no barriers: occupancy is VGPR-bound

// Correctly-rounded-to-f32 exp (f64 Cody-Waite + degree-13 Horner).
// Bit-matches np.exp->f32 (absmax 0.0 verified rounds 2/4/5/6/8/9/10).
// Deterministic -> recomputing it yields identical bits (fallback relies on this).
__device__ __forceinline__ float exp_cr(float xf) {
    double x = (double)xf;
    x = (x < -150.0) ? -150.0 : x;
    double t = x * 1.4426950408889634074;
    double nd = rint(t);
    double r = fma(nd, -6.93147180369123816490e-01, x);
    r = fma(nd, -1.90821492927058770002e-10, r);
    double p = 1.0 / 6227020800.0;
    p = fma(p, r, 1.0 / 479001600.0);
    p = fma(p, r, 1.0 / 39916800.0);
    p = fma(p, r, 1.0 / 3628800.0);
    p = fma(p, r, 1.0 / 362880.0);
    p = fma(p, r, 1.0 / 40320.0);
    p = fma(p, r, 1.0 / 5040.0);
    p = fma(p, r, 1.0 / 720.0);
    p = fma(p, r, 1.0 / 120.0);
    p = fma(p, r, 1.0 / 24.0);
    p = fma(p, r, 1.0 / 6.0);
    p = fma(p, r, 0.5);
    p = fma(p, r, 1.0);
    p = fma(p, r, 1.0);
    long long ni = (long long)nd;
    double sc = __longlong_as_double((1023LL + ni) << 52);
    return (float)(p * sc);
}

__global__ __launch_bounds__(TPB, 4) void ssd_decode_kernel(
    const float* __restrict__ inp,      // [N, 85]
    const float* __restrict__ priors,   // [N, 4]
    const float* __restrict__ var,      // [2]
    const float* __restrict__ thr,      // [1]
    float* __restrict__ out,            // 12N flat: boxes 4N | conf N | pred N | det 6N
    int n)
{
    const int i = blockIdx.x * TPB + threadIdx.x;   // prior index
    if (i >= n) return;

    // ---- load own row straight to registers: 85 independent dword loads.
    //      340B lane stride; each row = 6 cache lines, fully consumed by
    //      construction (no over-fetch). No LDS -> no 22KB tile -> occupancy
    //      16 waves/CU instead of 5-7: latency hidden by TLP, not structure.
    const float* row = inp + (long long)i * ROW;
    float lg[ROW];
    #pragma unroll
    for (int k = 0; k < ROW; ++k) lg[k] = row[k];

    // ---- pass A: max logit (8-way tree, regs; fmax associative+exact) ----
    float mx[8];
    #pragma unroll
    for (int j = 0; j < 8; ++j) mx[j] = lg[4 + j];
    #pragma unroll
    for (int k = 1; k < 10; ++k)
        #pragma unroll
        for (int j = 0; j < 8; ++j) mx[j] = fmaxf(mx[j], lg[4 + k * 8 + j]);
    float m = fmaxf(fmaxf(fmaxf(mx[0], mx[1]), fmaxf(mx[2], mx[3])),
                    fmaxf(fmaxf(mx[4], mx[5]), fmaxf(mx[6], mx[7])));
    m = fmaxf(m, lg[84]);

    // ---- pass B (fast): d = l - m (exact f32 sub), candidate count,
    //      hardware-exp sum (same 8-acc order as r10). Tie needs
    //      e >= 1-8*2^-24 i.e. d >= -4.8e-7; window -2^-20 = 2x margin. ----
    int nc = 0;
    int amf = 127;
    float racc[8];
    #pragma unroll
    for (int j = 0; j < 8; ++j) racc[j] = 0.0f;
    #pragma unroll
    for (int k = 0; k < 10; ++k)
        #pragma unroll
        for (int j = 0; j < 8; ++j) {
            int c = k * 8 + j;
            float d = lg[4 + c] - m;
            nc  += (d >= -9.5367431640625e-07f) ? 1 : 0;
            int cand = (d == 0.0f) ? c : 127;
            amf = (cand < amf) ? cand : amf;
            racc[j] += __expf(d);
        }
    float s1 = ((racc[0] + racc[1]) + (racc[2] + racc[3]))
             + ((racc[4] + racc[5]) + (racc[6] + racc[7]));
    {
        float d80 = lg[84] - m;
        nc  += (d80 >= -9.5367431640625e-07f) ? 1 : 0;
        int cand = (d80 == 0.0f) ? 80 : 127;
        amf = (cand < amf) ? cand : amf;
        s1 += __expf(d80);
    }

    int am;
    float conf;
    if (__any(nc > 1)) {
        // ---- exact fallback (cold, ~6% of waves; math identical to the
        //      proven r8/r10 path): np-bitwise e via exp_cr recomputed from
        //      the still-live lg[] regs (deterministic -> same bits as if
        //      stored), np-pairwise sum, IEEE-div boundary walk, descending
        //      first-tie scan. ----
        float racx[8];
        #pragma unroll
        for (int j = 0; j < 8; ++j) racx[j] = 0.0f;
        #pragma unroll
        for (int k = 0; k < 10; ++k)
            #pragma unroll
            for (int j = 0; j < 8; ++j)
                racx[j] += exp_cr(lg[4 + k * 8 + j] - m);
        float s = ((racx[0] + racx[1]) + (racx[2] + racx[3]))
                + ((racx[4] + racx[5]) + (racx[6] + racx[7]));
        s += exp_cr(lg[84] - m);

        float pmax = 1.0f / s;
        float t = 1.0f;
        #pragma unroll
        for (int k = 0; k < 8; ++k) {
            float tn = __uint_as_float(__float_as_uint(t) - 1u);
            t = ((tn / s) == pmax) ? tn : t;
        }
        am = 81;
        #pragma unroll
        for (int c = 80; c >= 0; --c)
            am = (exp_cr(lg[4 + c] - m) >= t) ? c : am;   // descending keeps FIRST
        conf = pmax;
    } else {
        am = amf;
        conf = 1.0f / s1;
    }

    // ---- decode box (2% threshold: hardware exp is plenty) ----
    float l0 = lg[0], l1 = lg[1], l2 = lg[2], l3 = lg[3];
    float4 pr = reinterpret_cast<const float4*>(priors)[i];
    float v0 = var[0], v1 = var[1];
    float cx = pr.x + l0 * v0 * pr.z;
    float cy = pr.y + l1 * v0 * pr.w;
    float w  = pr.z * __expf(l2 * v1);
    float h  = pr.w * __expf(l3 * v1);
    float x0 = cx - w * 0.5f;
    float y0 = cy - h * 0.5f;
    float x1 = x0 + w;
    float y1 = y0 + h;

    bool valid = (am > 0) && (conf > thr[0]);

    float4 box;
    box.x = valid ? x0 : 0.0f;
    box.y = valid ? y0 : 0.0f;
    box.z = valid ? x1 : 0.0f;
    box.w = valid ? y1 : 0.0f;
    float cz = valid ? conf : 0.0f;
    float pz = valid ? (float)(am - 1) : -1.0f;

    reinterpret_cast<float4*>(out)[i] = box;         // boxes [N,4]
    out[(long long)4 * n + i] = cz;                  // class_conf [N]
    out[(long long)5 * n + i] = pz;                  // class_pred [N] (as f32)
    float2* det2 = reinterpret_cast<float2*>(out + (long long)6 * n + (long long)i * 6);
    det2[0] = make_float2(box.x, box.y);
    det2[1] = make_float2(box.z, box.w);
    det2[2] = make_float2(cz, pz);
}

extern "C" void kernel_launch(void* const* d_in, const int* in_sizes, int n_in,
                              void* d_out, int out_size, void* d_ws, size_t ws_size,
                              hipStream_t stream)
{
    const float* inp    = (const float*)d_in[0];
    const float* priors = (const float*)d_in[1];
    const float* var    = (const float*)d_in[2];
    const float* thr    = (const float*)d_in[3];
    float* out = (float*)d_out;

    int n = in_sizes[1] / 4;              // priors has N*4 elements
    int blocks = (n + TPB - 1) / TPB;     // 262144/256 = 1024 blocks
    ssd_decode_kernel<<<blocks, TPB, 0, stream>>>(inp, priors, var, thr, out, n);
}